// Round 9
// baseline (142.641 us; speedup 1.0000x reference)
//
#include <hip/hip_runtime.h>

#define VOCAB 10000
#define EMB   16
#define HID   32
#define BATCH 4096
#define TLEN  512

typedef float v2f __attribute__((ext_vector_type(2)));
typedef float v4f __attribute__((ext_vector_type(4)));

// ---------------------------------------------------------------------------
// Kernel 1: P[v][j] = b[j] + sum_e emb[v][e] * Wx[e][j]   (fp32 table in ws)
// ---------------------------------------------------------------------------
__global__ __launch_bounds__(256) void rnn_proj(
    const float* __restrict__ emb, const float* __restrict__ Wx,
    const float* __restrict__ bias, float* __restrict__ P)
{
    int tid = blockIdx.x * 256 + threadIdx.x;
    if (tid >= VOCAB * HID) return;
    int v = tid >> 5;
    int j = tid & 31;
    float acc = bias[j];
    const float* ev = emb + v * EMB;
#pragma unroll
    for (int e = 0; e < EMB; ++e) {
        acc = fmaf(ev[e], Wx[e * HID + j], acc);
    }
    P[tid] = acc;
}

// ---------------------------------------------------------------------------
// Kernel 2: K-split scan, remat-proofed + pk-packed.
// One batch per wave (4096 waves = 4/SIMD). Lane = (j = lane&31, kh =
// lane>>5). Each lane: half-dot over its 16 i-values as 8 v_pk_fma_f32;
// halves combined with one __shfl_xor(part, 32). h in a wave-private LDS
// row (no barriers).
//
// waves_per_eu(4,4): pins occupancy at exactly 4 waves/SIMD -> 64-VGPR
// budget (r7's min-only hint let the allocator target 28 VGPRs and
// rematerialize w[] from GLOBAL MEMORY every step — the ~2x instr bloat).
// The empty asm on each w2[] element makes remat illegal.
// ---------------------------------------------------------------------------
__global__ __launch_bounds__(256)
__attribute__((amdgpu_waves_per_eu(4, 4)))
void rnn_scan(
    const int*   __restrict__ x,   const float* __restrict__ P,
    const float* __restrict__ Wh,  const float* __restrict__ Wd,
    const float* __restrict__ bd,  float* __restrict__ out)
{
    __shared__ float h_lds[4][HID];             // 1 row per wave, 512 B

    const int lane = threadIdx.x & 63;
    const int wave = threadIdx.x >> 6;
    const int j    = lane & 31;
    const int kh   = lane >> 5;                 // k-half: i in [kh*16, kh*16+16)
    const int b    = blockIdx.x * 4 + wave;

    // w2[m] = { Wh[kh*16+2m][j], Wh[kh*16+2m+1][j] } -> 8 v2f = 16 VGPRs
    v2f w2[8];
#pragma unroll
    for (int m = 0; m < 8; ++m) {
        w2[m].x = Wh[(kh * 16 + 2 * m + 0) * HID + j];
        w2[m].y = Wh[(kh * 16 + 2 * m + 1) * HID + j];
    }
    // pin into VGPRs; compiler can no longer rematerialize from memory
#pragma unroll
    for (int m = 0; m < 8; ++m) asm volatile("" : "+v"(w2[m]));

    h_lds[wave][j] = 0.0f;                      // h0 (2 lanes same addr+value: ok)

    const int* xb = x + b * TLEN;               // wave-uniform -> SMEM loads

    // pipeline: pA = P(t), pB = P(t+1), tok2 = token(t+2)
    int   tok2 = xb[2];
    float pA = P[xb[0] * HID + j];
    float pB = P[xb[1] * HID + j];

    float hj = 0.0f;
    const float TWO_LOG2E = 2.8853900817779268f; // 2*log2(e)
    const v4f* hrow = (const v4f*)(&h_lds[wave][0]) + kh * 4;

    for (int t = 0; t < TLEN; ++t) {
        // prefetch token(t+3) (uniform index -> scalar); issue P(t+2)
        int   ti   = (t + 3 < TLEN) ? (t + 3) : (TLEN - 1);
        int   tok3 = xb[ti];
        float pC   = P[tok2 * HID + j];

        // half dot, packed: 8 pk_fma in 4 chains of depth 2
        v2f a0 = (v2f){0.f, 0.f}, a1 = (v2f){0.f, 0.f};
        v2f a2 = (v2f){0.f, 0.f}, a3 = (v2f){0.f, 0.f};
#pragma unroll
        for (int q = 0; q < 2; ++q) {
            v4f u = hrow[2 * q];                // h[kh*16+8q .. +3]
            v4f v = hrow[2 * q + 1];            // h[kh*16+8q+4 .. +7]
            a0 = __builtin_elementwise_fma((v2f){u.x, u.y}, w2[4 * q + 0], a0);
            a1 = __builtin_elementwise_fma((v2f){u.z, u.w}, w2[4 * q + 1], a1);
            a2 = __builtin_elementwise_fma((v2f){v.x, v.y}, w2[4 * q + 2], a2);
            a3 = __builtin_elementwise_fma((v2f){v.z, v.w}, w2[4 * q + 3], a3);
        }
        v2f ps  = (a0 + a1) + (a2 + a3);
        float part = ps.x + ps.y;

        // combine the two k-halves (partner lane = lane ^ 32)
        part += __shfl_xor(part, 32, 64);
        float z = pA + part;

        // tanh(z) = 1 - 2/(e^{2z}+1); saturates cleanly (inf -> 1, 0 -> -1)
        float e2 = __builtin_amdgcn_exp2f(z * TWO_LOG2E);
        float r  = __builtin_amdgcn_rcpf(e2 + 1.0f);
        hj = fmaf(-2.0f, r, 1.0f);

        h_lds[wave][j] = hj;                    // both halves write same value

        pA = pB; pB = pC; tok2 = tok3;
    }

    // out[b] = sigmoid(sum_j h_j * Wd[j] + bd)
    float s = hj * Wd[j];
#pragma unroll
    for (int off = 16; off > 0; off >>= 1)
        s += __shfl_xor(s, off, 32);            // reduce within 32-lane group
    if (lane == 0) {
        float logit = s + bd[0];
        out[b] = 1.0f / (1.0f + __expf(-logit)); // fp32 output
    }
}

// ---------------------------------------------------------------------------
extern "C" void kernel_launch(void* const* d_in, const int* in_sizes, int n_in,
                              void* d_out, int out_size, void* d_ws, size_t ws_size,
                              hipStream_t stream)
{
    const int*   x   = (const int*)  d_in[0];
    const float* emb = (const float*)d_in[1];
    const float* Wx  = (const float*)d_in[2];
    const float* Wh  = (const float*)d_in[3];
    const float* bia = (const float*)d_in[4];
    const float* Wd  = (const float*)d_in[5];
    const float* bd  = (const float*)d_in[6];
    float* out = (float*)d_out;

    float* P = (float*)d_ws;                    // VOCAB*HID*4 = 1.28 MB

    rnn_proj<<<(VOCAB * HID + 255) / 256, 256, 0, stream>>>(emb, Wx, bia, P);
    rnn_scan<<<BATCH / 4, 256, 0, stream>>>(x, P, Wh, Wd, bd, out);
}

// Round 10
// 101.092 us; speedup vs baseline: 1.4110x; 1.4110x over previous
//
#include <hip/hip_runtime.h>

#define VOCAB 10000
#define EMB   16
#define HID   32
#define BATCH 4096
#define TLEN  512

typedef float v4f __attribute__((ext_vector_type(4)));

// ---------------------------------------------------------------------------
// Kernel 1: P[v][j] = b[j] + sum_e emb[v][e] * Wx[e][j]   (fp32 table in ws)
// ---------------------------------------------------------------------------
__global__ __launch_bounds__(256) void rnn_proj(
    const float* __restrict__ emb, const float* __restrict__ Wx,
    const float* __restrict__ bias, float* __restrict__ P)
{
    int tid = blockIdx.x * 256 + threadIdx.x;
    if (tid >= VOCAB * HID) return;
    int v = tid >> 5;
    int j = tid & 31;
    float acc = bias[j];
    const float* ev = emb + v * EMB;
#pragma unroll
    for (int e = 0; e < EMB; ++e) {
        acc = fmaf(ev[e], Wx[e * HID + j], acc);
    }
    P[tid] = acc;
}

// ---------------------------------------------------------------------------
// Kernel 2: lean unrolled scan (r6 structure, overhead amortized).
// Wave = 2 batches x 32 j-lanes; lane computes the FULL 32-FMA dot for its
// (batch, j) — no shuffles. h in wave-private LDS rows, broadcast float4
// reads, no barriers. 4x unrolled main loop:
//   - tokens loaded as int4 quads (1 VMEM per 4 steps, per-lane addressing
//     covers both batches in the same instruction)
//   - P rows prefetched one full quad ahead (~1200cy cover for ~200cy L2)
//   - no per-step pipeline moves / bounds selects (tail handled by clamp)
// NOTE: scalar fmaf only — v_pk_fma_f32 halves issue slots but not VALU
// pipe occupancy (2x work/lane) and lengthens chains; measured regression
// in r8/r9.
// ---------------------------------------------------------------------------
__global__ __launch_bounds__(256)
__attribute__((amdgpu_waves_per_eu(2, 2)))
void rnn_scan(
    const int*   __restrict__ x,   const float* __restrict__ P,
    const float* __restrict__ Wh,  const float* __restrict__ Wd,
    const float* __restrict__ bd,  float* __restrict__ out)
{
    __shared__ float h_lds[8][HID];             // 2 rows per wave, 1 KB

    const int lane = threadIdx.x & 63;
    const int wave = threadIdx.x >> 6;
    const int half = lane >> 5;
    const int j    = lane & 31;
    const int hb   = wave * 2 + half;           // wave-private row
    const int b    = blockIdx.x * 8 + hb;

    // Wh column j -> 32 VGPRs, pinned against rematerialization
    float whc[HID];
#pragma unroll
    for (int i = 0; i < HID; ++i) whc[i] = Wh[i * HID + j];
#pragma unroll
    for (int i = 0; i < HID; ++i) asm("" : "+v"(whc[i]));

    h_lds[hb][j] = 0.0f;                        // h0 = 0 (wave-private)

    const int* xb = x + b * TLEN;

    // token quads: tq_nxt = tokens for quad k+1
    int4 tq_cur = *(const int4*)(xb);           // steps 0..3
    int4 tq_nxt = *(const int4*)(xb + 4);       // steps 4..7

    // P values for current quad (prologue: accept the one-time latency)
    float pc0 = P[tq_cur.x * HID + j];
    float pc1 = P[tq_cur.y * HID + j];
    float pc2 = P[tq_cur.z * HID + j];
    float pc3 = P[tq_cur.w * HID + j];

    float hj = 0.0f;
    const float TWO_LOG2E = 2.8853900817779268f;  // 2*log2(e)
    const v4f* hrow = (const v4f*)(&h_lds[hb][0]);

#define STEP(PV)                                                           \
    {                                                                      \
        v4f u0 = hrow[0], u1 = hrow[1], u2 = hrow[2], u3 = hrow[3];        \
        v4f u4 = hrow[4], u5 = hrow[5], u6 = hrow[6], u7 = hrow[7];        \
        float a0 = (PV), a1 = 0.f, a2 = 0.f, a3 = 0.f;                     \
        a0 = fmaf(u0.x, whc[0],  a0); a1 = fmaf(u0.y, whc[1],  a1);        \
        a2 = fmaf(u0.z, whc[2],  a2); a3 = fmaf(u0.w, whc[3],  a3);        \
        a0 = fmaf(u1.x, whc[4],  a0); a1 = fmaf(u1.y, whc[5],  a1);        \
        a2 = fmaf(u1.z, whc[6],  a2); a3 = fmaf(u1.w, whc[7],  a3);        \
        a0 = fmaf(u2.x, whc[8],  a0); a1 = fmaf(u2.y, whc[9],  a1);        \
        a2 = fmaf(u2.z, whc[10], a2); a3 = fmaf(u2.w, whc[11], a3);        \
        a0 = fmaf(u3.x, whc[12], a0); a1 = fmaf(u3.y, whc[13], a1);        \
        a2 = fmaf(u3.z, whc[14], a2); a3 = fmaf(u3.w, whc[15], a3);        \
        a0 = fmaf(u4.x, whc[16], a0); a1 = fmaf(u4.y, whc[17], a1);        \
        a2 = fmaf(u4.z, whc[18], a2); a3 = fmaf(u4.w, whc[19], a3);        \
        a0 = fmaf(u5.x, whc[20], a0); a1 = fmaf(u5.y, whc[21], a1);        \
        a2 = fmaf(u5.z, whc[22], a2); a3 = fmaf(u5.w, whc[23], a3);        \
        a0 = fmaf(u6.x, whc[24], a0); a1 = fmaf(u6.y, whc[25], a1);        \
        a2 = fmaf(u6.z, whc[26], a2); a3 = fmaf(u6.w, whc[27], a3);        \
        a0 = fmaf(u7.x, whc[28], a0); a1 = fmaf(u7.y, whc[29], a1);        \
        a2 = fmaf(u7.z, whc[30], a2); a3 = fmaf(u7.w, whc[31], a3);        \
        float z  = (a0 + a1) + (a2 + a3);                                  \
        float e2 = __builtin_amdgcn_exp2f(z * TWO_LOG2E);                  \
        float r  = __builtin_amdgcn_rcpf(e2 + 1.0f);                       \
        hj = fmaf(-2.0f, r, 1.0f);                                         \
        h_lds[hb][j] = hj;                                                 \
    }

    const int NQ = TLEN / 4;                    // 128 quads, exact

    for (int k = 0; k < NQ; ++k) {
        // prefetch P rows for quad k+1 (tokens already resident in tq_nxt)
        float pn0 = P[tq_nxt.x * HID + j];
        float pn1 = P[tq_nxt.y * HID + j];
        float pn2 = P[tq_nxt.z * HID + j];
        float pn3 = P[tq_nxt.w * HID + j];
        // prefetch token quad k+2 (clamped; tail values unused)
        int q2 = (k + 2 < NQ) ? (k + 2) : (NQ - 1);
        int4 tq2 = *(const int4*)(xb + 4 * q2);

        STEP(pc0)
        STEP(pc1)
        STEP(pc2)
        STEP(pc3)

        pc0 = pn0; pc1 = pn1; pc2 = pn2; pc3 = pn3;
        tq_nxt = tq2;
    }
#undef STEP

    // out[b] = sigmoid(sum_j h_j * Wd[j] + bd)
    float s = hj * Wd[j];
#pragma unroll
    for (int off = 16; off > 0; off >>= 1)
        s += __shfl_xor(s, off, 32);            // reduce within 32-lane half
    if (j == 0) {
        float logit = s + bd[0];
        out[b] = 1.0f / (1.0f + __expf(-logit)); // fp32 output
    }
}

// ---------------------------------------------------------------------------
extern "C" void kernel_launch(void* const* d_in, const int* in_sizes, int n_in,
                              void* d_out, int out_size, void* d_ws, size_t ws_size,
                              hipStream_t stream)
{
    const int*   x   = (const int*)  d_in[0];
    const float* emb = (const float*)d_in[1];
    const float* Wx  = (const float*)d_in[2];
    const float* Wh  = (const float*)d_in[3];
    const float* bia = (const float*)d_in[4];
    const float* Wd  = (const float*)d_in[5];
    const float* bd  = (const float*)d_in[6];
    float* out = (float*)d_out;

    float* P = (float*)d_ws;                    // VOCAB*HID*4 = 1.28 MB

    rnn_proj<<<(VOCAB * HID + 255) / 256, 256, 0, stream>>>(emb, Wx, bia, P);
    rnn_scan<<<BATCH / 8, 256, 0, stream>>>(x, P, Wh, Wd, bd, out);
}

// Round 11
// 88.983 us; speedup vs baseline: 1.6030x; 1.1361x over previous
//
#include <hip/hip_runtime.h>

#define VOCAB 10000
#define EMB   16
#define HID   32
#define BATCH 4096
#define TLEN  512

typedef _Float16 f16x2 __attribute__((ext_vector_type(2)));
typedef _Float16 f16x8 __attribute__((ext_vector_type(8)));

// ---------------------------------------------------------------------------
// Kernel 1: P[v][j] = b[j] + sum_e emb[v][e] * Wx[e][j]   (fp32 table in ws)
// ---------------------------------------------------------------------------
__global__ __launch_bounds__(256) void rnn_proj(
    const float* __restrict__ emb, const float* __restrict__ Wx,
    const float* __restrict__ bias, float* __restrict__ P)
{
    int tid = blockIdx.x * 256 + threadIdx.x;
    if (tid >= VOCAB * HID) return;
    int v = tid >> 5;
    int j = tid & 31;
    float acc = bias[j];
    const float* ev = emb + v * EMB;
#pragma unroll
    for (int e = 0; e < EMB; ++e) {
        acc = fmaf(ev[e], Wx[e * HID + j], acc);
    }
    P[tid] = acc;
}

// ---------------------------------------------------------------------------
// Kernel 2: fp16/dot2 scan (r10 structure, both bottleneck terms halved).
// Wave = 2 batches x 32 j-lanes, full dot per lane, no shuffles, no
// barriers (wave-private LDS rows).
//   - h stored as fp16 in LDS: row = 64 B -> 4 ds_read_b128 (was 8), LDS
//     broadcast-return bytes halved (the ~256cy/CU-step invariant term).
//   - dot product as 16 v_dot2_f32_f16 (fp32 accumulate) instead of 32
//     v_fma_f32: halves the dominant VALU-issue block.
//   - fp16 error budget: dynamics measured strongly contracting (r6/r10
//     absmax=0 vs bf16-rounded ref); h err ~5e-4/step -> output err ~5e-4
//     vs threshold 1.18e-2. P stays fp32.
//   - r10's 4x unroll, int4 token quads, P prefetched one quad ahead.
// ---------------------------------------------------------------------------
__global__ __launch_bounds__(256)
__attribute__((amdgpu_waves_per_eu(2, 2)))
void rnn_scan(
    const int*   __restrict__ x,   const float* __restrict__ P,
    const float* __restrict__ Wh,  const float* __restrict__ Wd,
    const float* __restrict__ bd,  float* __restrict__ out)
{
    __shared__ _Float16 h_lds[8][HID];          // 8 rows x 64 B

    const int lane = threadIdx.x & 63;
    const int wave = threadIdx.x >> 6;
    const int half = lane >> 5;
    const int j    = lane & 31;
    const int hb   = wave * 2 + half;           // wave-private row
    const int b    = blockIdx.x * 8 + hb;

    // Wh column j as fp16 pairs: wh2[m] = { Wh[2m][j], Wh[2m+1][j] }
    f16x2 wh2[16];
#pragma unroll
    for (int m = 0; m < 16; ++m) {
        wh2[m] = (f16x2){ (_Float16)Wh[(2 * m + 0) * HID + j],
                          (_Float16)Wh[(2 * m + 1) * HID + j] };
    }
#pragma unroll
    for (int m = 0; m < 16; ++m) asm("" : "+v"(wh2[m]));  // remat-proof

    h_lds[hb][j] = (_Float16)0.0f;              // h0 = 0 (wave-private)

    const int* xb = x + b * TLEN;

    // pipeline prologue: tokens for quads 0 and 1, P values for quad 0
    int4 tq_cur = *(const int4*)(xb);           // steps 0..3
    int4 tq_nxt = *(const int4*)(xb + 4);       // steps 4..7
    float pc0 = P[tq_cur.x * HID + j];
    float pc1 = P[tq_cur.y * HID + j];
    float pc2 = P[tq_cur.z * HID + j];
    float pc3 = P[tq_cur.w * HID + j];

    float hj = 0.0f;
    const float TWO_LOG2E = 2.8853900817779268f;  // 2*log2(e)
    const f16x8* hrow = (const f16x8*)(&h_lds[hb][0]);

#define PAIR(U, A, B) __builtin_shufflevector((U), (U), (A), (B))
#define STEP(PV)                                                              \
    {                                                                         \
        f16x8 u0 = hrow[0], u1 = hrow[1], u2 = hrow[2], u3 = hrow[3];         \
        float a0 = (PV), a1 = 0.f, a2 = 0.f, a3 = 0.f;                        \
        a0 = __builtin_amdgcn_fdot2(PAIR(u0,0,1), wh2[0],  a0, false);        \
        a1 = __builtin_amdgcn_fdot2(PAIR(u0,2,3), wh2[1],  a1, false);        \
        a2 = __builtin_amdgcn_fdot2(PAIR(u0,4,5), wh2[2],  a2, false);        \
        a3 = __builtin_amdgcn_fdot2(PAIR(u0,6,7), wh2[3],  a3, false);        \
        a0 = __builtin_amdgcn_fdot2(PAIR(u1,0,1), wh2[4],  a0, false);        \
        a1 = __builtin_amdgcn_fdot2(PAIR(u1,2,3), wh2[5],  a1, false);        \
        a2 = __builtin_amdgcn_fdot2(PAIR(u1,4,5), wh2[6],  a2, false);        \
        a3 = __builtin_amdgcn_fdot2(PAIR(u1,6,7), wh2[7],  a3, false);        \
        a0 = __builtin_amdgcn_fdot2(PAIR(u2,0,1), wh2[8],  a0, false);        \
        a1 = __builtin_amdgcn_fdot2(PAIR(u2,2,3), wh2[9],  a1, false);        \
        a2 = __builtin_amdgcn_fdot2(PAIR(u2,4,5), wh2[10], a2, false);        \
        a3 = __builtin_amdgcn_fdot2(PAIR(u2,6,7), wh2[11], a3, false);        \
        a0 = __builtin_amdgcn_fdot2(PAIR(u3,0,1), wh2[12], a0, false);        \
        a1 = __builtin_amdgcn_fdot2(PAIR(u3,2,3), wh2[13], a1, false);        \
        a2 = __builtin_amdgcn_fdot2(PAIR(u3,4,5), wh2[14], a2, false);        \
        a3 = __builtin_amdgcn_fdot2(PAIR(u3,6,7), wh2[15], a3, false);        \
        float z  = (a0 + a1) + (a2 + a3);                                     \
        float e2 = __builtin_amdgcn_exp2f(z * TWO_LOG2E);                     \
        float r  = __builtin_amdgcn_rcpf(e2 + 1.0f);                          \
        hj = fmaf(-2.0f, r, 1.0f);                                            \
        h_lds[hb][j] = (_Float16)hj;                                          \
    }

    const int NQ = TLEN / 4;                    // 128 quads, exact

    for (int k = 0; k < NQ; ++k) {
        // prefetch P rows for quad k+1 (tokens already resident in tq_nxt)
        float pn0 = P[tq_nxt.x * HID + j];
        float pn1 = P[tq_nxt.y * HID + j];
        float pn2 = P[tq_nxt.z * HID + j];
        float pn3 = P[tq_nxt.w * HID + j];
        // prefetch token quad k+2 (clamped; tail values unused)
        int q2 = (k + 2 < NQ) ? (k + 2) : (NQ - 1);
        int4 tq2 = *(const int4*)(xb + 4 * q2);

        STEP(pc0)
        STEP(pc1)
        STEP(pc2)
        STEP(pc3)

        pc0 = pn0; pc1 = pn1; pc2 = pn2; pc3 = pn3;
        tq_nxt = tq2;
    }
#undef STEP
#undef PAIR

    // out[b] = sigmoid(sum_j h_j * Wd[j] + bd)
    float s = hj * Wd[j];
#pragma unroll
    for (int off = 16; off > 0; off >>= 1)
        s += __shfl_xor(s, off, 32);            // reduce within 32-lane half
    if (j == 0) {
        float logit = s + bd[0];
        out[b] = 1.0f / (1.0f + __expf(-logit)); // fp32 output
    }
}

// ---------------------------------------------------------------------------
extern "C" void kernel_launch(void* const* d_in, const int* in_sizes, int n_in,
                              void* d_out, int out_size, void* d_ws, size_t ws_size,
                              hipStream_t stream)
{
    const int*   x   = (const int*)  d_in[0];
    const float* emb = (const float*)d_in[1];
    const float* Wx  = (const float*)d_in[2];
    const float* Wh  = (const float*)d_in[3];
    const float* bia = (const float*)d_in[4];
    const float* Wd  = (const float*)d_in[5];
    const float* bd  = (const float*)d_in[6];
    float* out = (float*)d_out;

    float* P = (float*)d_ws;                    // VOCAB*HID*4 = 1.28 MB

    rnn_proj<<<(VOCAB * HID + 255) / 256, 256, 0, stream>>>(emb, Wx, bia, P);
    rnn_scan<<<BATCH / 8, 256, 0, stream>>>(x, P, Wh, Wd, bd, out);
}